// Round 1
// baseline (212.277 us; speedup 1.0000x reference)
//
#include <hip/hip_runtime.h>
#include <math.h>
#include <float.h>

#define BB 16
#define NN 2382
#define HH 8
#define EPSF 1e-5f

// ws float layout (tiny: params only; Y lives in d_out)
#define WS_A1 0
#define WS_C1 8
#define WS_WQ 16
#define WS_WK 24
#define WS_WV 32
#define WS_W2 96
#define WS_S2 112

__global__ __launch_bounds__(256) void k1_params(
    const float* __restrict__ z,  const float* __restrict__ w1,
    const float* __restrict__ g1, const float* __restrict__ be1,
    const float* __restrict__ wq, const float* __restrict__ wk,
    const float* __restrict__ wv, const float* __restrict__ w2,
    float* __restrict__ ws)
{
    __shared__ float sh[8];
    const int tid = threadIdx.x;
    float s = 0.f, s2 = 0.f;
    for (int i = tid; i < BB*NN; i += 256) {
        float v = z[i]; s += v; s2 = fmaf(v, v, s2);
    }
    #pragma unroll
    for (int off = 32; off; off >>= 1) {
        s  += __shfl_xor(s, off);
        s2 += __shfl_xor(s2, off);
    }
    if ((tid & 63) == 0) { sh[tid>>6] = s; sh[4+(tid>>6)] = s2; }
    __syncthreads();
    if (tid != 0) return;

    const float sum = sh[0]+sh[1]+sh[2]+sh[3];
    const float sq  = sh[4]+sh[5]+sh[6]+sh[7];
    const float invn = 1.f / (float)(BB*NN);
    const float mz = sum * invn;
    const float vz = sq * invn - mz*mz;

    float n1=0.f, nq=0.f, nk=0.f, n2=0.f;
    #pragma unroll
    for (int h=0; h<8; ++h) {
        n1 = fmaf(w1[h], w1[h], n1);
        nq = fmaf(wq[h], wq[h], nq);
        nk = fmaf(wk[h], wk[h], nk);
        n2 = fmaf(w2[h], w2[h], n2);
    }
    n1 = sqrtf(n1); nq = sqrtf(nq); nk = sqrtf(nk); n2 = sqrtf(n2);

    // sigma_max(wv) via power iteration on M = wv^T wv (wv is (O,C) row-major)
    float M[64];
    for (int i=0;i<8;++i)
      for (int j=0;j<8;++j) {
        float a=0.f;
        for (int o=0;o<8;++o) a = fmaf(wv[o*8+i], wv[o*8+j], a);
        M[i*8+j]=a;
      }
    float u[8];
    #pragma unroll
    for (int i=0;i<8;++i) u[i]=1.f;
    float lam = 0.f;
    for (int it=0; it<64; ++it) {
        float t[8]; float nr=0.f;
        #pragma unroll
        for (int i=0;i<8;++i) {
            float a=0.f;
            #pragma unroll
            for (int j=0;j<8;++j) a = fmaf(M[i*8+j], u[j], a);
            t[i]=a; nr = fmaf(a,a,nr);
        }
        nr = sqrtf(nr);
        lam = nr;
        const float in_ = 1.f/nr;
        #pragma unroll
        for (int i=0;i<8;++i) u[i]=t[i]*in_;
    }
    const float invsig = 1.f / sqrtf(lam);

    for (int h=0; h<8; ++h) {
        const float w1n = w1[h]/n1;
        const float rs = rsqrtf(fmaf(w1n*w1n, vz, EPSF));
        const float a = w1n*rs*g1[h];
        ws[WS_A1+h] = a;                 // x_h = relu(a*z + c)
        ws[WS_C1+h] = be1[h] - mz*a;     // (b1 cancels in train-mode BN)
        ws[WS_WQ+h] = wq[h]/nq;
        ws[WS_WK+h] = wk[h]/nk;
        ws[WS_W2+h] = w2[h]/n2;
    }
    for (int i=0;i<64;++i) ws[WS_WV+i] = wv[i]*invsig;
}

// One block per (n-chunk, batch). Stages per-batch K (N floats) and V (N x 8)
// in LDS (recomputed from z via the folded BN1 affine), then each thread owns
// one n: serial reduction over m with broadcast (conflict-free) LDS reads.
__global__ __launch_bounds__(256) void k3_attn(
    const float* __restrict__ z, const float* __restrict__ bqp,
    const float* __restrict__ bkp, const float* __restrict__ bvp,
    const float* __restrict__ gammap, const float* __restrict__ b2p,
    const float* __restrict__ ws, float* __restrict__ yout)
{
    extern __shared__ __align__(16) float lds[];
    float* sV   = lds;           // NN*8
    float* sK   = lds + NN*8;    // NN
    float* sred = lds + NN*9;    // 8
    const int b = blockIdx.y;
    const int tid = threadIdx.x;

    float a1[8], c1[8], wqn[8], wkn[8], w2n[8], bv[8], wvn[64];
    #pragma unroll
    for (int i=0;i<8;++i){
        a1[i]=ws[WS_A1+i]; c1[i]=ws[WS_C1+i]; wqn[i]=ws[WS_WQ+i];
        wkn[i]=ws[WS_WK+i]; w2n[i]=ws[WS_W2+i]; bv[i]=bvp[i];
    }
    #pragma unroll
    for (int i=0;i<64;++i) wvn[i]=ws[WS_WV+i];
    const float bq=bqp[0], bk=bkp[0], b2=b2p[0], gamma=gammap[0];
    const float* __restrict__ zb = z + b*NN;

    float lmax=-FLT_MAX, lmin=FLT_MAX;
    for (int m=tid; m<NN; m+=256) {
        const float zv = zb[m];
        float xh[8];
        #pragma unroll
        for (int h=0;h<8;++h) xh[h] = fmaxf(fmaf(a1[h], zv, c1[h]), 0.f);
        float kk = bk;
        #pragma unroll
        for (int h=0;h<8;++h) kk = fmaf(wkn[h], xh[h], kk);
        sK[m] = kk;
        lmax = fmaxf(lmax, kk); lmin = fminf(lmin, kk);
        #pragma unroll
        for (int o=0;o<8;++o) {
            float v = bv[o];
            #pragma unroll
            for (int c=0;c<8;++c) v = fmaf(wvn[o*8+c], xh[c], v);
            sV[m*8+o] = v;
        }
    }
    #pragma unroll
    for (int off=32; off; off>>=1) {
        lmax = fmaxf(lmax, __shfl_xor(lmax, off));
        lmin = fminf(lmin, __shfl_xor(lmin, off));
    }
    if ((tid & 63)==0){ sred[tid>>6]=lmax; sred[4+(tid>>6)]=lmin; }
    __syncthreads();
    const float kmax = fmaxf(fmaxf(sred[0],sred[1]), fmaxf(sred[2],sred[3]));
    const float kmin = fminf(fminf(sred[4],sred[5]), fminf(sred[6],sred[7]));

    const int n = blockIdx.x*256 + tid;
    if (n >= NN) return;
    const float zv = zb[n];
    float xh[8];
    #pragma unroll
    for (int h=0;h<8;++h) xh[h] = fmaxf(fmaf(a1[h], zv, c1[h]), 0.f);
    float q = bq;
    #pragma unroll
    for (int h=0;h<8;++h) q = fmaf(wqn[h], xh[h], q);
    const float s = (q >= 0.f) ? q*kmax : q*kmin;  // max_m q*k_m

    float den = 0.f;
    float acc[8] = {0,0,0,0,0,0,0,0};
    #pragma unroll 2
    for (int m=0; m<NN; ++m) {
        const float e = __expf(fmaf(q, sK[m], -s));
        const float4 va = *(const float4*)(sV + m*8);
        const float4 vb = *(const float4*)(sV + m*8 + 4);
        den += e;
        acc[0]=fmaf(e,va.x,acc[0]); acc[1]=fmaf(e,va.y,acc[1]);
        acc[2]=fmaf(e,va.z,acc[2]); acc[3]=fmaf(e,va.w,acc[3]);
        acc[4]=fmaf(e,vb.x,acc[4]); acc[5]=fmaf(e,vb.y,acc[5]);
        acc[6]=fmaf(e,vb.z,acc[6]); acc[7]=fmaf(e,vb.w,acc[7]);
    }
    const float inv = 1.f/den;
    float y = b2;
    #pragma unroll
    for (int h=0;h<8;++h) y = fmaf(w2n[h], fmaf(gamma, acc[h]*inv, xh[h]), y);
    yout[b*NN + n] = y;
}

__global__ __launch_bounds__(256) void k4_stats(
    const float* __restrict__ y, float* __restrict__ ws,
    const float* __restrict__ g2, const float* __restrict__ be2)
{
    __shared__ float sh[8];
    const int tid = threadIdx.x;
    float s=0.f, s2=0.f;
    for (int i=tid; i<BB*NN; i+=256){ float v=y[i]; s+=v; s2=fmaf(v,v,s2); }
    #pragma unroll
    for (int off=32; off; off>>=1){ s+=__shfl_xor(s,off); s2+=__shfl_xor(s2,off); }
    if((tid&63)==0){ sh[tid>>6]=s; sh[4+(tid>>6)]=s2; }
    __syncthreads();
    if (tid) return;
    const float sum=sh[0]+sh[1]+sh[2]+sh[3];
    const float sq =sh[4]+sh[5]+sh[6]+sh[7];
    const float invn = 1.f/(float)(BB*NN);
    const float m = sum*invn;
    const float v = sq*invn - m*m;
    const float sc = g2[0]*rsqrtf(v+EPSF);
    ws[WS_S2]   = sc;
    ws[WS_S2+1] = be2[0] - m*sc;
}

__global__ __launch_bounds__(256) void k5_out(
    const float* __restrict__ ws, float* __restrict__ out)
{
    const int i = blockIdx.x*256 + threadIdx.x;
    if (i >= BB*NN) return;
    const float sc = ws[WS_S2], sh = ws[WS_S2+1];
    out[i] = fmaxf(fmaf(out[i], sc, sh), 0.f);
}

extern "C" void kernel_launch(void* const* d_in, const int* in_sizes, int n_in,
                              void* d_out, int out_size, void* d_ws, size_t ws_size,
                              hipStream_t stream)
{
    const float* z    = (const float*)d_in[0];
    const float* w1   = (const float*)d_in[1];
    // d_in[2] = b1 (cancels in train-mode BN1)
    const float* g1   = (const float*)d_in[3];
    const float* be1  = (const float*)d_in[4];
    const float* wq   = (const float*)d_in[5];
    const float* bq   = (const float*)d_in[6];
    const float* wk   = (const float*)d_in[7];
    const float* bk   = (const float*)d_in[8];
    const float* wv   = (const float*)d_in[9];
    const float* bv   = (const float*)d_in[10];
    const float* gamma= (const float*)d_in[11];
    const float* w2   = (const float*)d_in[12];
    const float* b2   = (const float*)d_in[13];
    const float* g2   = (const float*)d_in[14];
    const float* be2  = (const float*)d_in[15];
    float* ws  = (float*)d_ws;
    float* out = (float*)d_out;

    k1_params<<<1, 256, 0, stream>>>(z, w1, g1, be1, wq, wk, wv, w2, ws);

    const size_t lds_bytes = (size_t)(NN*9 + 8) * sizeof(float);
    k3_attn<<<dim3((NN+255)/256, BB), 256, lds_bytes, stream>>>(
        z, bq, bk, bv, gamma, b2, ws, out);   // y staged in d_out

    k4_stats<<<1, 256, 0, stream>>>(out, ws, g2, be2);

    k5_out<<<(BB*NN+255)/256, 256, 0, stream>>>(ws, out);
}

// Round 2
// 64.811 us; speedup vs baseline: 3.2753x; 3.2753x over previous
//
#include <hip/hip_runtime.h>
#include <math.h>
#include <float.h>

#define BB 16
#define NN 2382
#define EPSF 1e-5f
#define NTILE 64
#define CHM 596            // ceil(NN/4)
#define NV4 9528           // BB*NN/4

// ws float layout (params only; Y staged in d_out)
#define WS_A1  0
#define WS_C1  8
#define WS_WQ  16
#define WS_WK  24
#define WS_WVP 32
#define WS_BVP 40
#define WS_W2  48
#define WS_S2  56

__global__ __launch_bounds__(256) void k1_params(
    const float* __restrict__ z,  const float* __restrict__ w1,
    const float* __restrict__ g1, const float* __restrict__ be1,
    const float* __restrict__ wq, const float* __restrict__ wk,
    const float* __restrict__ wv, const float* __restrict__ w2,
    const float* __restrict__ bv, float* __restrict__ ws)
{
    __shared__ float sh[8];
    const int tid = threadIdx.x;
    const float4* __restrict__ z4 = (const float4*)z;
    float s = 0.f, s2 = 0.f;
    for (int i = tid; i < NV4; i += 256) {
        float4 v = z4[i];
        s += v.x + v.y + v.z + v.w;
        s2 = fmaf(v.x,v.x, fmaf(v.y,v.y, fmaf(v.z,v.z, fmaf(v.w,v.w, s2))));
    }
    #pragma unroll
    for (int off = 32; off; off >>= 1) {
        s  += __shfl_xor(s, off);
        s2 += __shfl_xor(s2, off);
    }
    if ((tid & 63) == 0) { sh[tid>>6] = s; sh[4+(tid>>6)] = s2; }
    __syncthreads();
    if (tid != 0) return;

    const float sum = sh[0]+sh[1]+sh[2]+sh[3];
    const float sq  = sh[4]+sh[5]+sh[6]+sh[7];
    const float invn = 1.f / (float)(BB*NN);
    const float mz = sum * invn;
    const float vz = sq * invn - mz*mz;

    float n1=0.f, nq=0.f, nk=0.f, n2=0.f;
    #pragma unroll
    for (int h=0; h<8; ++h) {
        n1 = fmaf(w1[h], w1[h], n1);
        nq = fmaf(wq[h], wq[h], nq);
        nk = fmaf(wk[h], wk[h], nk);
        n2 = fmaf(w2[h], w2[h], n2);
    }
    n1 = sqrtf(n1); nq = sqrtf(nq); nk = sqrtf(nk); n2 = sqrtf(n2);

    // sigma_max(wv) via power iteration on M = wv^T wv
    float M[64];
    for (int i=0;i<8;++i)
      for (int j=0;j<8;++j) {
        float a=0.f;
        for (int o=0;o<8;++o) a = fmaf(wv[o*8+i], wv[o*8+j], a);
        M[i*8+j]=a;
      }
    float u[8];
    #pragma unroll
    for (int i=0;i<8;++i) u[i]=1.f;
    float lam = 0.f;
    for (int it=0; it<64; ++it) {
        float t[8]; float nr=0.f;
        #pragma unroll
        for (int i=0;i<8;++i) {
            float a=0.f;
            #pragma unroll
            for (int j=0;j<8;++j) a = fmaf(M[i*8+j], u[j], a);
            t[i]=a; nr = fmaf(a,a,nr);
        }
        nr = sqrtf(nr);
        lam = nr;
        const float in_ = 1.f/nr;
        #pragma unroll
        for (int i=0;i<8;++i) u[i]=t[i]*in_;
    }
    const float invsig = 1.f / sqrtf(lam);

    float w2n[8];
    for (int h=0; h<8; ++h) {
        const float w1n = w1[h]/n1;
        const float rs = rsqrtf(fmaf(w1n*w1n, vz, EPSF));
        const float a = w1n*rs*g1[h];
        ws[WS_A1+h] = a;                 // x_h = relu(a*z + c)
        ws[WS_C1+h] = be1[h] - mz*a;     // (b1 cancels in train-mode BN)
        ws[WS_WQ+h] = wq[h]/nq;
        ws[WS_WK+h] = wk[h]/nk;
        w2n[h] = w2[h]/n2;
        ws[WS_W2+h] = w2n[h];
    }
    // P-projection: P[m] = sum_c wvP[c]*x_c[m] + bvP, with
    // wvP[c] = sum_h w2n[h]*wv_sn[h,c], bvP = sum_h w2n[h]*bv[h]
    for (int c=0;c<8;++c) {
        float a=0.f;
        for (int h=0;h<8;++h) a = fmaf(w2n[h], wv[h*8+c]*invsig, a);
        ws[WS_WVP+c] = a;
    }
    float bp=0.f;
    for (int h=0;h<8;++h) bp = fmaf(w2n[h], bv[h], bp);
    ws[WS_BVP] = bp;
}

// Block = (n-tile of 64, batch). 4 waves: wave w reduces m-chunk w for all
// 64 n's (lane = n). K,P staged per batch in LDS as float2 (broadcast reads).
__global__ __launch_bounds__(256) void k3_attn(
    const float* __restrict__ z, const float* __restrict__ bqp,
    const float* __restrict__ bkp, const float* __restrict__ gammap,
    const float* __restrict__ b2p, const float* __restrict__ ws,
    float* __restrict__ yout)
{
    __shared__ float2 sKP[NN];     // {K[m], P[m]}
    __shared__ float2 sPart[256];  // per-(wave,lane) {den, num}
    __shared__ float  sred[8];
    const int b = blockIdx.y;
    const int tid = threadIdx.x;
    const int wave = tid >> 6, lane = tid & 63;

    float a1[8], c1[8], wqn[8], wkn[8], w2n[8], wvP[8];
    #pragma unroll
    for (int i=0;i<8;++i){
        a1[i]=ws[WS_A1+i]; c1[i]=ws[WS_C1+i]; wqn[i]=ws[WS_WQ+i];
        wkn[i]=ws[WS_WK+i]; w2n[i]=ws[WS_W2+i]; wvP[i]=ws[WS_WVP+i];
    }
    const float bq=bqp[0], bk=bkp[0], b2=b2p[0], gamma=gammap[0];
    const float bvP=ws[WS_BVP];
    const float* __restrict__ zb = z + b*NN;

    float lmax=-FLT_MAX, lmin=FLT_MAX;
    for (int m=tid; m<NN; m+=256) {
        const float zv = zb[m];
        float xh[8];
        #pragma unroll
        for (int h=0;h<8;++h) xh[h] = fmaxf(fmaf(a1[h], zv, c1[h]), 0.f);
        float kk = bk, pp = bvP;
        #pragma unroll
        for (int h=0;h<8;++h) { kk = fmaf(wkn[h], xh[h], kk); pp = fmaf(wvP[h], xh[h], pp); }
        sKP[m] = make_float2(kk, pp);
        lmax = fmaxf(lmax, kk); lmin = fminf(lmin, kk);
    }
    #pragma unroll
    for (int off=32; off; off>>=1) {
        lmax = fmaxf(lmax, __shfl_xor(lmax, off));
        lmin = fminf(lmin, __shfl_xor(lmin, off));
    }
    if (lane==0){ sred[wave]=lmax; sred[4+wave]=lmin; }
    __syncthreads();
    const float kmax = fmaxf(fmaxf(sred[0],sred[1]), fmaxf(sred[2],sred[3]));
    const float kmin = fminf(fminf(sred[4],sred[5]), fminf(sred[6],sred[7]));

    const int n = blockIdx.x*NTILE + lane;
    float q = 0.f, r = 0.f;
    if (n < NN) {
        const float zv = zb[n];
        float xh[8];
        #pragma unroll
        for (int h=0;h<8;++h) xh[h] = fmaxf(fmaf(a1[h], zv, c1[h]), 0.f);
        q = bq; r = b2;
        #pragma unroll
        for (int h=0;h<8;++h) { q = fmaf(wqn[h], xh[h], q); r = fmaf(w2n[h], xh[h], r); }
    }
    const float s = (q >= 0.f) ? q*kmax : q*kmin;   // max_m q*K[m]

    const int m0 = wave*CHM;
    const int m1 = (m0 + CHM < NN) ? m0 + CHM : NN;
    float den0=0.f, den1=0.f, num0=0.f, num1=0.f;
    int m = m0;
    #pragma unroll 4
    for (; m+2 <= m1; m += 2) {
        const float2 kp0 = sKP[m];
        const float2 kp1 = sKP[m+1];
        const float e0 = __expf(fmaf(q, kp0.x, -s));
        const float e1 = __expf(fmaf(q, kp1.x, -s));
        den0 += e0; num0 = fmaf(e0, kp0.y, num0);
        den1 += e1; num1 = fmaf(e1, kp1.y, num1);
    }
    if (m < m1) {
        const float2 kp = sKP[m];
        const float e = __expf(fmaf(q, kp.x, -s));
        den0 += e; num0 = fmaf(e, kp.y, num0);
    }
    sPart[tid] = make_float2(den0+den1, num0+num1);
    __syncthreads();
    if (tid < NTILE && n < NN) {
        const float2 p0 = sPart[tid];
        const float2 p1 = sPart[64+tid];
        const float2 p2 = sPart[128+tid];
        const float2 p3 = sPart[192+tid];
        const float den = p0.x+p1.x+p2.x+p3.x;
        const float num = p0.y+p1.y+p2.y+p3.y;
        yout[b*NN + n] = r + gamma*num/den;
    }
}

__global__ __launch_bounds__(256) void k4_stats(
    const float* __restrict__ y, float* __restrict__ ws,
    const float* __restrict__ g2, const float* __restrict__ be2)
{
    __shared__ float sh[8];
    const int tid = threadIdx.x;
    const float4* __restrict__ y4 = (const float4*)y;
    float s=0.f, s2=0.f;
    for (int i=tid; i<NV4; i+=256){
        float4 v = y4[i];
        s += v.x + v.y + v.z + v.w;
        s2 = fmaf(v.x,v.x, fmaf(v.y,v.y, fmaf(v.z,v.z, fmaf(v.w,v.w, s2))));
    }
    #pragma unroll
    for (int off=32; off; off>>=1){ s+=__shfl_xor(s,off); s2+=__shfl_xor(s2,off); }
    if((tid&63)==0){ sh[tid>>6]=s; sh[4+(tid>>6)]=s2; }
    __syncthreads();
    if (tid) return;
    const float sum=sh[0]+sh[1]+sh[2]+sh[3];
    const float sq =sh[4]+sh[5]+sh[6]+sh[7];
    const float invn = 1.f/(float)(BB*NN);
    const float m = sum*invn;
    const float v = sq*invn - m*m;
    const float sc = g2[0]*rsqrtf(v+EPSF);
    ws[WS_S2]   = sc;
    ws[WS_S2+1] = be2[0] - m*sc;
}

__global__ __launch_bounds__(256) void k5_out(
    const float* __restrict__ ws, float* __restrict__ out)
{
    const int i = blockIdx.x*256 + threadIdx.x;
    if (i >= NV4) return;
    const float sc = ws[WS_S2], sh = ws[WS_S2+1];
    float4* o4 = (float4*)out;
    float4 v = o4[i];
    v.x = fmaxf(fmaf(v.x, sc, sh), 0.f);
    v.y = fmaxf(fmaf(v.y, sc, sh), 0.f);
    v.z = fmaxf(fmaf(v.z, sc, sh), 0.f);
    v.w = fmaxf(fmaf(v.w, sc, sh), 0.f);
    o4[i] = v;
}

extern "C" void kernel_launch(void* const* d_in, const int* in_sizes, int n_in,
                              void* d_out, int out_size, void* d_ws, size_t ws_size,
                              hipStream_t stream)
{
    const float* z    = (const float*)d_in[0];
    const float* w1   = (const float*)d_in[1];
    // d_in[2] = b1 (cancels in train-mode BN1)
    const float* g1   = (const float*)d_in[3];
    const float* be1  = (const float*)d_in[4];
    const float* wq   = (const float*)d_in[5];
    const float* bq   = (const float*)d_in[6];
    const float* wk   = (const float*)d_in[7];
    const float* bk   = (const float*)d_in[8];
    const float* wv   = (const float*)d_in[9];
    const float* bv   = (const float*)d_in[10];
    const float* gamma= (const float*)d_in[11];
    const float* w2   = (const float*)d_in[12];
    const float* b2   = (const float*)d_in[13];
    const float* g2   = (const float*)d_in[14];
    const float* be2  = (const float*)d_in[15];
    float* ws  = (float*)d_ws;
    float* out = (float*)d_out;

    k1_params<<<1, 256, 0, stream>>>(z, w1, g1, be1, wq, wk, wv, w2, bv, ws);

    k3_attn<<<dim3((NN+NTILE-1)/NTILE, BB), 256, 0, stream>>>(
        z, bq, bk, gamma, b2, ws, out);   // y staged in d_out

    k4_stats<<<1, 256, 0, stream>>>(out, ws, g2, be2);

    k5_out<<<(NV4+255)/256, 256, 0, stream>>>(ws, out);
}

// Round 3
// 50.941 us; speedup vs baseline: 4.1671x; 1.2723x over previous
//
#include <hip/hip_runtime.h>
#include <math.h>
#include <float.h>

#define BB 16
#define NN 2382
#define EPSF 1e-5f
#define NTILE 64
#define CHM 596            // ceil(NN/4)
#define NV4 9528           // BB*NN/4
#define L2E 1.4426950408889634f

// ws float layout
#define WS_A1    0
#define WS_C1    8
#define WS_WQ    16
#define WS_WK    24
#define WS_WVP   32
#define WS_BVP   40
#define WS_W2    48
#define WS_SUM   56
#define WS_SUMSQ 57

__global__ __launch_bounds__(256) void k1_params(
    const float* __restrict__ z,  const float* __restrict__ w1,
    const float* __restrict__ g1, const float* __restrict__ be1,
    const float* __restrict__ wq, const float* __restrict__ wk,
    const float* __restrict__ wv, const float* __restrict__ w2,
    const float* __restrict__ bv, float* __restrict__ ws)
{
    __shared__ float sh[8];
    const int tid = threadIdx.x;
    const float4* __restrict__ z4 = (const float4*)z;
    float s = 0.f, s2 = 0.f;
    #pragma unroll 4
    for (int i = tid; i < NV4; i += 256) {
        float4 v = z4[i];
        s += v.x + v.y + v.z + v.w;
        s2 = fmaf(v.x,v.x, fmaf(v.y,v.y, fmaf(v.z,v.z, fmaf(v.w,v.w, s2))));
    }
    #pragma unroll
    for (int off = 32; off; off >>= 1) {
        s  += __shfl_xor(s, off);
        s2 += __shfl_xor(s2, off);
    }
    if ((tid & 63) == 0) { sh[tid>>6] = s; sh[4+(tid>>6)] = s2; }
    __syncthreads();
    if (tid >= 64) return;

    const float sum = sh[0]+sh[1]+sh[2]+sh[3];
    const float sq  = sh[4]+sh[5]+sh[6]+sh[7];
    const float invn = 1.f / (float)(BB*NN);
    const float mz = sum * invn;
    const float vz = sq * invn - mz*mz;

    // ---- wave-parallel power iteration on M = wv^T wv (lane = (i,j)) ----
    const int pi = tid >> 3, pj = tid & 7;
    float Mij = 0.f;
    #pragma unroll
    for (int o = 0; o < 8; ++o) Mij = fmaf(wv[o*8+pi], wv[o*8+pj], Mij);
    float u = 1.f, nr = 1.f;
    for (int it = 0; it < 48; ++it) {
        float a = Mij * u;
        a += __shfl_xor(a, 1); a += __shfl_xor(a, 2); a += __shfl_xor(a, 4);   // t_i (all lanes of row i)
        float bb = a * a;
        bb += __shfl_xor(bb, 8); bb += __shfl_xor(bb, 16); bb += __shfl_xor(bb, 32); // sum_i t_i^2
        nr = sqrtf(bb);
        const float tj = __shfl(a, pj << 3);   // t at row j
        u = tj / nr;
    }
    const float invsig = rsqrtf(nr);           // 1/sigma_max(wv)

    // ---- per-h params on lanes 0..7 ----
    float w1h=0.f, wqh=0.f, wkh=0.f, w2h=0.f, g1h=0.f, be1h=0.f, bvh=0.f;
    if (tid < 8) {
        w1h=w1[tid]; wqh=wq[tid]; wkh=wk[tid]; w2h=w2[tid];
        g1h=g1[tid]; be1h=be1[tid]; bvh=bv[tid];
    }
    float t;
    t = w1h*w1h; t += __shfl_xor(t,1); t += __shfl_xor(t,2); t += __shfl_xor(t,4);
    const float n1 = sqrtf(t);
    t = wqh*wqh; t += __shfl_xor(t,1); t += __shfl_xor(t,2); t += __shfl_xor(t,4);
    const float nq = sqrtf(t);
    t = wkh*wkh; t += __shfl_xor(t,1); t += __shfl_xor(t,2); t += __shfl_xor(t,4);
    const float nk = sqrtf(t);
    t = w2h*w2h; t += __shfl_xor(t,1); t += __shfl_xor(t,2); t += __shfl_xor(t,4);
    const float n2 = sqrtf(t);

    const float w2n = w2h / n2;
    // wvP[c] = invsig * sum_h w2n_h * wv[h,c]   (lane c computes)
    float wvPc = 0.f;
    #pragma unroll
    for (int h = 0; h < 8; ++h)
        wvPc = fmaf(__shfl(w2n, h), (tid < 8 ? wv[h*8+tid] : 0.f), wvPc);
    wvPc *= invsig;
    // bvP = sum_h w2n_h * bv_h
    t = w2n * bvh; t += __shfl_xor(t,1); t += __shfl_xor(t,2); t += __shfl_xor(t,4);
    const float bvP = t;

    if (tid < 8) {
        const float w1n = w1h / n1;
        const float rs = rsqrtf(fmaf(w1n*w1n, vz, EPSF));
        const float a1 = w1n * rs * g1h;
        ws[WS_A1+tid]  = a1;                 // x_h = relu(a1*z + c1)
        ws[WS_C1+tid]  = be1h - mz*a1;       // (b1 cancels in train-mode BN)
        ws[WS_WQ+tid]  = wqh / nq;
        ws[WS_WK+tid]  = wkh / nk;
        ws[WS_W2+tid]  = w2n;
        ws[WS_WVP+tid] = wvPc;
        if (tid == 0) {
            ws[WS_BVP]   = bvP;
            ws[WS_SUM]   = 0.f;              // zero y-stat accumulators each call
            ws[WS_SUMSQ] = 0.f;
        }
    }
}

// Block = (n-tile of 64, batch). 4 waves: wave w reduces m-chunk w for all
// 64 n's (lane = n). K,P staged per batch in LDS as float2; read as float4.
// Epilogue: block-partial y stats -> atomicAdd into ws.
__global__ __launch_bounds__(256) void k3_attn(
    const float* __restrict__ z, const float* __restrict__ bqp,
    const float* __restrict__ bkp, const float* __restrict__ gammap,
    const float* __restrict__ b2p, const float* __restrict__ ws,
    float* __restrict__ yout)
{
    __shared__ float2 sKP[NN];     // {K[m], P[m]}
    __shared__ float2 sPart[256];  // per-(wave,lane) {den, num}
    __shared__ float  sred[8];
    const int b = blockIdx.y;
    const int tid = threadIdx.x;
    const int wave = tid >> 6, lane = tid & 63;

    float a1[8], c1[8], wqn[8], wkn[8], w2n[8], wvP[8];
    #pragma unroll
    for (int i=0;i<8;++i){
        a1[i]=ws[WS_A1+i]; c1[i]=ws[WS_C1+i]; wqn[i]=ws[WS_WQ+i];
        wkn[i]=ws[WS_WK+i]; w2n[i]=ws[WS_W2+i]; wvP[i]=ws[WS_WVP+i];
    }
    const float bq=bqp[0], bk=bkp[0], b2=b2p[0], gamma=gammap[0];
    const float bvP=ws[WS_BVP];
    const float* __restrict__ zb = z + b*NN;

    float lmax=-FLT_MAX, lmin=FLT_MAX;
    for (int m=tid; m<NN; m+=256) {
        const float zv = zb[m];
        float xh[8];
        #pragma unroll
        for (int h=0;h<8;++h) xh[h] = fmaxf(fmaf(a1[h], zv, c1[h]), 0.f);
        float kk = bk, pp = bvP;
        #pragma unroll
        for (int h=0;h<8;++h) { kk = fmaf(wkn[h], xh[h], kk); pp = fmaf(wvP[h], xh[h], pp); }
        sKP[m] = make_float2(kk, pp);
        lmax = fmaxf(lmax, kk); lmin = fminf(lmin, kk);
    }
    #pragma unroll
    for (int off=32; off; off>>=1) {
        lmax = fmaxf(lmax, __shfl_xor(lmax, off));
        lmin = fminf(lmin, __shfl_xor(lmin, off));
    }
    if (lane==0){ sred[wave]=lmax; sred[4+wave]=lmin; }
    __syncthreads();
    const float kmax = fmaxf(fmaxf(sred[0],sred[1]), fmaxf(sred[2],sred[3]));
    const float kmin = fminf(fminf(sred[4],sred[5]), fminf(sred[6],sred[7]));

    const int n = blockIdx.x*NTILE + lane;
    float q = 0.f, r = 0.f;
    if (n < NN) {
        const float zv = zb[n];
        float xh[8];
        #pragma unroll
        for (int h=0;h<8;++h) xh[h] = fmaxf(fmaf(a1[h], zv, c1[h]), 0.f);
        q = bq; r = b2;
        #pragma unroll
        for (int h=0;h<8;++h) { q = fmaf(wqn[h], xh[h], q); r = fmaf(w2n[h], xh[h], r); }
    }
    const float s = (q >= 0.f) ? q*kmax : q*kmin;   // max_m q*K[m]
    const float q2 = q * L2E;
    const float s2 = s * L2E;

    const int m0 = wave*CHM;
    const int m1 = (m0 + CHM < NN) ? m0 + CHM : NN;   // even count, m0 even
    float den0=0.f, den1=0.f, num0=0.f, num1=0.f;
    #pragma unroll 4
    for (int m = m0; m+2 <= m1; m += 2) {
        const float4 kp = *(const float4*)(&sKP[m]);  // {K[m],P[m],K[m+1],P[m+1]}
        const float e0 = __builtin_amdgcn_exp2f(fmaf(q2, kp.x, -s2));
        const float e1 = __builtin_amdgcn_exp2f(fmaf(q2, kp.z, -s2));
        den0 += e0; num0 = fmaf(e0, kp.y, num0);
        den1 += e1; num1 = fmaf(e1, kp.w, num1);
    }
    sPart[tid] = make_float2(den0+den1, num0+num1);
    __syncthreads();

    float yv = 0.f;
    if (tid < NTILE && n < NN) {
        const float2 p0 = sPart[tid];
        const float2 p1 = sPart[64+tid];
        const float2 p2 = sPart[128+tid];
        const float2 p3 = sPart[192+tid];
        const float den = p0.x+p1.x+p2.x+p3.x;
        const float num = p0.y+p1.y+p2.y+p3.y;
        yv = r + gamma*num/den;
        yout[b*NN + n] = yv;
    }
    if (tid < 64) {   // wave 0: block-partial y stats
        float sy = yv, sy2 = yv*yv;
        #pragma unroll
        for (int off=32; off; off>>=1) {
            sy  += __shfl_xor(sy,  off);
            sy2 += __shfl_xor(sy2, off);
        }
        if (tid == 0) {
            atomicAdd((float*)&ws[WS_SUM],   sy);
            atomicAdd((float*)&ws[WS_SUMSQ], sy2);
        }
    }
}

__global__ __launch_bounds__(256) void k5_out(
    const float* __restrict__ ws, const float* __restrict__ g2,
    const float* __restrict__ be2, float* __restrict__ out)
{
    const int i = blockIdx.x*256 + threadIdx.x;
    if (i >= NV4) return;
    const float invn = 1.f/(float)(BB*NN);
    const float m  = ws[WS_SUM]*invn;
    const float vv = ws[WS_SUMSQ]*invn - m*m;
    const float sc = g2[0]*rsqrtf(vv+EPSF);
    const float sh = be2[0] - m*sc;
    float4* o4 = (float4*)out;
    float4 v = o4[i];
    v.x = fmaxf(fmaf(v.x, sc, sh), 0.f);
    v.y = fmaxf(fmaf(v.y, sc, sh), 0.f);
    v.z = fmaxf(fmaf(v.z, sc, sh), 0.f);
    v.w = fmaxf(fmaf(v.w, sc, sh), 0.f);
    o4[i] = v;
}

extern "C" void kernel_launch(void* const* d_in, const int* in_sizes, int n_in,
                              void* d_out, int out_size, void* d_ws, size_t ws_size,
                              hipStream_t stream)
{
    const float* z    = (const float*)d_in[0];
    const float* w1   = (const float*)d_in[1];
    // d_in[2] = b1 (cancels in train-mode BN1)
    const float* g1   = (const float*)d_in[3];
    const float* be1  = (const float*)d_in[4];
    const float* wq   = (const float*)d_in[5];
    const float* bq   = (const float*)d_in[6];
    const float* wk   = (const float*)d_in[7];
    const float* bk   = (const float*)d_in[8];
    const float* wv   = (const float*)d_in[9];
    const float* bv   = (const float*)d_in[10];
    const float* gamma= (const float*)d_in[11];
    const float* w2   = (const float*)d_in[12];
    const float* b2   = (const float*)d_in[13];
    const float* g2   = (const float*)d_in[14];
    const float* be2  = (const float*)d_in[15];
    float* ws  = (float*)d_ws;
    float* out = (float*)d_out;

    k1_params<<<1, 256, 0, stream>>>(z, w1, g1, be1, wq, wk, wv, w2, bv, ws);

    k3_attn<<<dim3((NN+NTILE-1)/NTILE, BB), 256, 0, stream>>>(
        z, bq, bk, gamma, b2, ws, out);   // y staged in d_out

    k5_out<<<(NV4+255)/256, 256, 0, stream>>>(ws, g2, be2, out);
}